// Round 1
// baseline (175.062 us; speedup 1.0000x reference)
//
#include <hip/hip_runtime.h>

#define NPIX (32*512*512)        // 8388608
#define BN_EPS 1e-5f

// ws float layout:
// [0..5]   M1 sums of s_i
// [6..26]  M2 sums of s_i*s_j (upper tri, idx = 6 + a*(11-a)/2 + b, a<=b)
// [27]     S1 (sum o_pre)
// [28]     S2 (sum o_pre^2)
// [29]     a2, [30] c2
// [32..232) wpack[25][8] = {a1*w1[0..5], beff, w2[c]}

__device__ __forceinline__ void stencil6(const float* __restrict__ x, int p, float s[6]) {
    int rem = p & (512*512 - 1);
    int i = rem >> 9, j = rem & 511;
    float c  = x[p];
    float n  = (i > 0)   ? x[p-512] : 0.f;
    float so = (i < 511) ? x[p+512] : 0.f;
    float w  = (j > 0)   ? x[p-1]   : 0.f;
    float e  = (j < 511) ? x[p+1]   : 0.f;
    float se = (i < 511 && j < 511) ? x[p+513] : 0.f;
    float nw = (i > 0   && j > 0)   ? x[p-513] : 0.f;
    s[0] = c;
    s[1] = (so - n) * 0.5f;      // p_x
    s[2] = (e - w) * 0.5f;       // p_y
    s[3] = so + n - 2.f*c;       // pp_x
    s[4] = e + w - 2.f*c;        // pp_y
    s[5] = se + nw - so - e;     // pp_xy
}

__global__ __launch_bounds__(256) void k_moments(const float* __restrict__ x, float* ws) {
    int t = threadIdx.x;
    int base = blockIdx.x * 8192;
    float acc[27];
    #pragma unroll
    for (int i = 0; i < 27; ++i) acc[i] = 0.f;
    for (int k = 0; k < 32; ++k) {
        int p = base + t + 256*k;
        float s[6];
        stencil6(x, p, s);
        #pragma unroll
        for (int a = 0; a < 6; ++a) {
            acc[a] += s[a];
            #pragma unroll
            for (int b = a; b < 6; ++b)
                acc[6 + a*(11-a)/2 + b] = fmaf(s[a], s[b], acc[6 + a*(11-a)/2 + b]);
        }
    }
    #pragma unroll
    for (int i = 0; i < 27; ++i) {
        float v = acc[i];
        for (int off = 32; off; off >>= 1) v += __shfl_xor(v, off);
        acc[i] = v;
    }
    __shared__ float red[27][4];
    int wave = t >> 6, lane = t & 63;
    if (lane == 0)
        for (int i = 0; i < 27; ++i) red[i][wave] = acc[i];
    __syncthreads();
    if (t < 27) atomicAdd(&ws[t], red[t][0] + red[t][1] + red[t][2] + red[t][3]);
}

__global__ void k_stats1(const float* w1, const float* b1, const float* g1,
                         const float* beta1, const float* w2, float* ws) {
    int c = threadIdx.x;
    if (c >= 25) return;
    const float invN = 1.f / (float)NPIX;
    float m1[6], wr[6];
    #pragma unroll
    for (int i = 0; i < 6; ++i) m1[i] = ws[i] * invN;
    #pragma unroll
    for (int i = 0; i < 6; ++i) wr[i] = w1[c*6 + i];
    float bc = b1[c];
    float mean = bc;
    #pragma unroll
    for (int i = 0; i < 6; ++i) mean = fmaf(wr[i], m1[i], mean);
    float e2 = bc * bc;
    #pragma unroll
    for (int i = 0; i < 6; ++i) e2 = fmaf(2.f*bc*wr[i], m1[i], e2);
    #pragma unroll
    for (int i = 0; i < 6; ++i)
        #pragma unroll
        for (int j = 0; j < 6; ++j) {
            int a = i < j ? i : j, b = i < j ? j : i;
            float m2 = ws[6 + a*(11-a)/2 + b] * invN;
            e2 = fmaf(wr[i]*wr[j], m2, e2);
        }
    float var = e2 - mean*mean;
    float a1 = g1[c] * rsqrtf(var + BN_EPS);
    float* wp = ws + 32 + c*8;
    #pragma unroll
    for (int i = 0; i < 6; ++i) wp[i] = a1 * wr[i];
    wp[6] = fmaf(a1, bc - mean, beta1[c]);
    wp[7] = w2[c];
}

__global__ __launch_bounds__(256) void k_main(const float* __restrict__ x, float* ws,
                                              const float* __restrict__ b2,
                                              float* __restrict__ opre) {
    __shared__ float4 wpack[25][2];
    int t = threadIdx.x;
    if (t < 200) ((float*)wpack)[t] = ws[32 + t];
    __syncthreads();
    int base = blockIdx.x * 2048;

    float s0[8], s1[8], s2[8], s3[8], s4[8], s5[8];
    #pragma unroll
    for (int k = 0; k < 8; ++k) {
        int p = base + t + 256*k;
        float s[6];
        stencil6(x, p, s);
        s0[k]=s[0]; s1[k]=s[1]; s2[k]=s[2]; s3[k]=s[3]; s4[k]=s[4]; s5[k]=s[5];
    }
    float o[8];
    float b2v = b2[0];
    #pragma unroll
    for (int k = 0; k < 8; ++k) o[k] = b2v;
    for (int c = 0; c < 25; ++c) {
        float4 wa = wpack[c][0];
        float4 wb = wpack[c][1];
        #pragma unroll
        for (int k = 0; k < 8; ++k) {
            float tt = wb.z;
            tt = fmaf(wa.x, s0[k], tt);
            tt = fmaf(wa.y, s1[k], tt);
            tt = fmaf(wa.z, s2[k], tt);
            tt = fmaf(wa.w, s3[k], tt);
            tt = fmaf(wb.x, s4[k], tt);
            tt = fmaf(wb.y, s5[k], tt);
            tt = fmaxf(tt, 0.f);
            o[k] = fmaf(wb.w, tt, o[k]);
        }
    }
    float l1 = 0.f, l2 = 0.f;
    #pragma unroll
    for (int k = 0; k < 8; ++k) {
        opre[base + t + 256*k] = o[k];
        l1 += o[k];
        l2 = fmaf(o[k], o[k], l2);
    }
    for (int off = 32; off; off >>= 1) { l1 += __shfl_xor(l1, off); l2 += __shfl_xor(l2, off); }
    __shared__ float red[2][4];
    int wave = t >> 6, lane = t & 63;
    if (lane == 0) { red[0][wave] = l1; red[1][wave] = l2; }
    __syncthreads();
    if (t == 0) atomicAdd(&ws[27], red[0][0]+red[0][1]+red[0][2]+red[0][3]);
    if (t == 1) atomicAdd(&ws[28], red[1][0]+red[1][1]+red[1][2]+red[1][3]);
}

__global__ void k_stats2(const float* g2, const float* beta2, float* ws) {
    const float invN = 1.f / (float)NPIX;
    float mean = ws[27] * invN;
    float var  = ws[28] * invN - mean*mean;
    float a2 = g2[0] * rsqrtf(var + BN_EPS);
    ws[29] = a2;
    ws[30] = fmaf(-mean, a2, beta2[0]);
}

__global__ __launch_bounds__(256) void k_final(const float* __restrict__ x, const float* ws,
                                               float* out) {
    int idx = blockIdx.x * 256 + threadIdx.x;   // float4 index
    float a2 = ws[29], c2 = ws[30];
    float4 o = ((const float4*)out)[idx];
    float4 xv = ((const float4*)x)[idx];
    float4 r;
    r.x = fmaxf(fmaf(a2, o.x, c2), 0.f) + xv.x;
    r.y = fmaxf(fmaf(a2, o.y, c2), 0.f) + xv.y;
    r.z = fmaxf(fmaf(a2, o.z, c2), 0.f) + xv.z;
    r.w = fmaxf(fmaf(a2, o.w, c2), 0.f) + xv.w;
    ((float4*)out)[idx] = r;
}

extern "C" void kernel_launch(void* const* d_in, const int* in_sizes, int n_in,
                              void* d_out, int out_size, void* d_ws, size_t ws_size,
                              hipStream_t stream) {
    const float* x     = (const float*)d_in[0];
    const float* w1    = (const float*)d_in[1];
    const float* b1    = (const float*)d_in[2];
    const float* g1    = (const float*)d_in[3];
    const float* beta1 = (const float*)d_in[4];
    const float* w2    = (const float*)d_in[5];
    const float* b2    = (const float*)d_in[6];
    const float* g2    = (const float*)d_in[7];
    const float* beta2 = (const float*)d_in[8];
    float* out = (float*)d_out;
    float* ws  = (float*)d_ws;

    hipMemsetAsync(ws, 0, 32 * sizeof(float), stream);
    k_moments<<<1024, 256, 0, stream>>>(x, ws);
    k_stats1 <<<1, 64, 0, stream>>>(w1, b1, g1, beta1, w2, ws);
    k_main   <<<4096, 256, 0, stream>>>(x, ws, b2, out);
    k_stats2 <<<1, 1, 0, stream>>>(g2, beta2, ws);
    k_final  <<<8192, 256, 0, stream>>>(x, ws, out);
}